// Round 7
// baseline (712.532 us; speedup 1.0000x reference)
//
#include <hip/hip_runtime.h>
#include <hip/hip_bf16.h>

// Swin block: B=8, H=W=128, C=192, NH=6, HD=32, WS=8, SHIFT=4, N=64, NW=256
// ROUND 13:
//  - bias/mask computed IN-KERNEL per softmax unit (16 rpb gathers, overlapped
//    with QK^T). Kills the bias-table prep, which correlated with a ~120us
//    total-vs-kall gap in R11/R12. prep = weight cvt only (R9: ~10us).
//  - ks-outer GEMM loops: A-frags read from LDS once per ks and reused across
//    all the wave's n-frags (was once per MFMA). LDS b128 reads/block
//    ~3700 -> ~1900 (R12 model: ~150us/CU of LDS read serialization).
//  - fc2: 6 waves x 2 n-frags (halves its LDS reads); P7 follows.
//  - final stores no longer non-temporal (NT 64B half-lines bypassed L2
//    merging -> WRITE_SIZE 241MB vs 96MB output).

typedef __hip_bfloat16 bf16;
typedef short bf16x8 __attribute__((ext_vector_type(8)));   // 8 bf16 = 4 VGPRs
typedef float f32x4 __attribute__((ext_vector_type(4)));

__device__ __forceinline__ bf16 f2b(float f) { return __float2bfloat16(f); }
// bf16 LDS swizzle: XOR row low bits into the 16B-granule index (8 bf16).
__device__ __forceinline__ int sw(int row, int col, int stride) {
    return row * stride + (col ^ ((row & 7) << 3));
}
// f32 LDS swizzle: XOR row low bits into the 16B-granule index (4 f32).
__device__ __forceinline__ int swf(int row, int col) {
    return row * 192 + (col ^ ((row & 7) << 2));
}

// workspace: fragment-ordered bf16 weights.
// weight element ((cb*KS + ks)*64 + lane)*8 + j == W[cb*16+(lane&15)][ks*32+(lane>>4)*8+j]
#define WQ_OFF 0        // qkv_w  [576][192]  cb=36 KS=6
#define WP_OFF 110592   // proj_w [192][192]  cb=12 KS=6
#define W1_OFF 147456   // fc1_w  [768][192]  cb=48 KS=6
#define W2_OFF 294912   // fc2_w  [192][768]  cb=12 KS=24
#define WS_ELEMS 442368

// ---- K0: one-shot fp32 -> bf16 fragment-order weight conversion ------------
__global__ __launch_bounds__(256) void w_cvt(const float* __restrict__ qw,
                                             const float* __restrict__ pw,
                                             const float* __restrict__ w1,
                                             const float* __restrict__ w2,
                                             bf16* __restrict__ ws) {
    int t = blockIdx.x * 256 + threadIdx.x;   // one 8-elem group per thread
    if (t >= 55296) return;                   // 442368/8
    const float* src; int K; int base; int g;
    if (t < 13824)      { src = qw; K = 192; base = WQ_OFF; g = t; }
    else if (t < 18432) { src = pw; K = 192; base = WP_OFF; g = t - 13824; }
    else if (t < 36864) { src = w1; K = 192; base = W1_OFF; g = t - 18432; }
    else                { src = w2; K = 768; base = W2_OFF; g = t - 36864; }
    int KS = K >> 5;
    int cb   = g / (KS * 64);
    int rem  = g % (KS * 64);
    int ks   = rem >> 6;
    int lane = rem & 63;
    int row  = cb * 16 + (lane & 15);
    int k0   = ks * 32 + (lane >> 4) * 8;
    bf16* dst = ws + base + (size_t)g * 8;
    const float* s = src + (size_t)row * K + k0;
#pragma unroll
    for (int j = 0; j < 8; ++j) dst[j] = f2b(s[j]);
}

// ---- K1: fully fused Swin block, one window (64 tokens) per block ----------
__global__ __launch_bounds__(1024, 4) void k_all(const float* __restrict__ x,
                                                 const float* __restrict__ g,
                                                 const float* __restrict__ bt,
                                                 const bf16* __restrict__ wsb,
                                                 const float* __restrict__ rpb,
                                                 const float* __restrict__ qbias,
                                                 const float* __restrict__ pbias,
                                                 const float* __restrict__ g2,
                                                 const float* __restrict__ bt2,
                                                 const float* __restrict__ b1,
                                                 const float* __restrict__ b2,
                                                 float* __restrict__ out) {
    // LDS (128 KB), regions reused across phases:
    //  R0 [0,24576)      Qs [64][192]swz         | P5+: As (LN2 tile)
    //  R1 [24576,49152)  Ks [64][192]swz         | P4+: o1f fp32 [64][192]swf
    //  R2 [49152,73728)  Vt [6][32][64]swz       |      (48KB, spans R1+R2)
    //  R3 [73728,98304)  A (LN1) == AO           | P6+: Hs [64][384]swz bf16
    //  R4 [98304,131072) Pb 16x2KB               |      (48KB, spans R3+24KB of R4)
    __shared__ __align__(16) char SM[131072];
    bf16* Qs = (bf16*)(SM);
    bf16* Ks = (bf16*)(SM + 24576);
    bf16* Vt = (bf16*)(SM + 49152);
    bf16* A  = (bf16*)(SM + 73728);
    bf16* AO = (bf16*)(SM + 73728);
    bf16* Pb = (bf16*)(SM + 98304);
    float* o1f = (float*)(SM + 24576);   // overlays Ks+Vt (dead after P3)
    bf16* As   = (bf16*)(SM);            // overlays Qs (dead after P3)
    bf16* Hs   = (bf16*)(SM + 73728);    // overlays AO+Pb (dead after P4/P3)

    int wid = blockIdx.x;
    int bz = wid >> 8, widx = wid & 255;
    int wh = widx >> 4, ww = widx & 15;
    int tid = threadIdx.x, wave = tid >> 6, lane = tid & 63;
    int l15 = lane & 15, l4 = lane >> 4;
    int kk0 = l4 << 3;
    const float SC = 0.1767766952966369f;  // 1/sqrt(32)
    bool ty = (wh == 15), tx = (ww == 15); // shifted-edge window flags

    // --- Phase 1: LN1 + cyclic shift -> A -----------------------------------
    {
        float g0 = g[lane], g1 = g[lane + 64], gx = g[lane + 128];
        float c0 = bt[lane], c1 = bt[lane + 64], c2 = bt[lane + 128];
        for (int t = wave; t < 64; t += 16) {
            int i = t >> 3, j = t & 7;
            int shr = (wh * 8 + i + 4) & 127;   // roll(-4)
            int shc = (ww * 8 + j + 4) & 127;
            const float* px = x + ((size_t)bz * 16384 + shr * 128 + shc) * 192;
            float v0 = px[lane], v1 = px[lane + 64], v2 = px[lane + 128];
            float s = v0 + v1 + v2, ss = v0 * v0 + v1 * v1 + v2 * v2;
#pragma unroll
            for (int o = 32; o > 0; o >>= 1) { s += __shfl_xor(s, o); ss += __shfl_xor(ss, o); }
            float mu = s * (1.f / 192.f);
            float var = fmaxf(ss * (1.f / 192.f) - mu * mu, 0.f);
            float rs = rsqrtf(var + 1e-5f);
            A[sw(t, lane, 192)]       = f2b((v0 - mu) * rs * g0 + c0);
            A[sw(t, lane + 64, 192)]  = f2b((v1 - mu) * rs * g1 + c1);
            A[sw(t, lane + 128, 192)] = f2b((v2 - mu) * rs * gx + c2);
        }
    }
    __syncthreads();

    // --- Phase 2: QKV GEMM, ks-outer (M=64, N=576, K=192) -------------------
    // 36 n-frags: every wave {wave, wave+16}; waves 0-3 also {wave+32}.
    {
        const bf16* Wq = wsb + WQ_OFF;
        int f0 = wave, f1 = wave + 16, f2 = wave + 32;
        f32x4 aA[4], aB[4], aC[4];
#pragma unroll
        for (int m = 0; m < 4; ++m) {
            aA[m] = (f32x4){0.f, 0.f, 0.f, 0.f};
            aB[m] = (f32x4){0.f, 0.f, 0.f, 0.f};
            aC[m] = (f32x4){0.f, 0.f, 0.f, 0.f};
        }
#pragma unroll
        for (int ks = 0; ks < 6; ++ks) {
            bf16x8 a[4];
#pragma unroll
            for (int m = 0; m < 4; ++m)
                a[m] = *(const bf16x8*)&A[sw(m * 16 + l15, ks * 32 + kk0, 192)];
            bf16x8 b0 = *(const bf16x8*)&Wq[(f0 * 6 + ks) * 512 + (lane << 3)];
            bf16x8 b1 = *(const bf16x8*)&Wq[(f1 * 6 + ks) * 512 + (lane << 3)];
#pragma unroll
            for (int m = 0; m < 4; ++m)
                aA[m] = __builtin_amdgcn_mfma_f32_16x16x32_bf16(a[m], b0, aA[m], 0, 0, 0);
#pragma unroll
            for (int m = 0; m < 4; ++m)
                aB[m] = __builtin_amdgcn_mfma_f32_16x16x32_bf16(a[m], b1, aB[m], 0, 0, 0);
            if (wave < 4) {
                bf16x8 bb2 = *(const bf16x8*)&Wq[(f2 * 6 + ks) * 512 + (lane << 3)];
#pragma unroll
                for (int m = 0; m < 4; ++m)
                    aC[m] = __builtin_amdgcn_mfma_f32_16x16x32_bf16(a[m], bb2, aC[m], 0, 0, 0);
            }
        }
        auto EPI = [&](int f, f32x4* acc) {
            int which = f / 12, cc = (f % 12) * 16 + l15;
            float qb = qbias[which * 192 + cc];
            if (which == 0) {
#pragma unroll
                for (int m = 0; m < 4; ++m)
#pragma unroll
                for (int r = 0; r < 4; ++r)
                    Qs[sw(m * 16 + (l4 << 2) + r, cc, 192)] = f2b((acc[m][r] + qb) * SC);
            } else if (which == 1) {
#pragma unroll
                for (int m = 0; m < 4; ++m)
#pragma unroll
                for (int r = 0; r < 4; ++r)
                    Ks[sw(m * 16 + (l4 << 2) + r, cc, 192)] = f2b(acc[m][r] + qb);
            } else {
                int head = (f % 12) >> 1, d = cc & 31;
#pragma unroll
                for (int m = 0; m < 4; ++m)
#pragma unroll
                for (int r = 0; r < 4; ++r)
                    Vt[head * 2048 + sw(d, m * 16 + (l4 << 2) + r, 64)] = f2b(acc[m][r] + qb);
            }
        };
        EPI(f0, aA);
        EPI(f1, aB);
        if (wave < 4) EPI(f2, aC);
    }
    __syncthreads();

    // --- Phase 3: attention. 24 units = (head, 16-q-row group) --------------
    {
        bf16* Pw = Pb + wave * 1024;   // wave-private [16][64] swz
#pragma unroll 1
        for (int ui = 0; ui < 2; ++ui) {
            int u = wave + ui * 16;
            if (u >= 24) break;
            int h = u >> 2, mqu = u & 3;
            // QK^T: S[16 q][64 key], K=32
            f32x4 S[4];
            bf16x8 qa = *(const bf16x8*)&Qs[sw(mqu * 16 + l15, h * 32 + kk0, 192)];
#pragma unroll
            for (int n = 0; n < 4; ++n) {
                bf16x8 kb = *(const bf16x8*)&Ks[sw(n * 16 + l15, h * 32 + kk0, 192)];
                S[n] = __builtin_amdgcn_mfma_f32_16x16x32_bf16(qa, kb, (f32x4){0.f,0.f,0.f,0.f}, 0, 0, 0);
            }
            // in-kernel bias/mask: 16 gathers from rpb (5.4KB, L1-resident),
            // label math only for edge windows (wave-uniform branch).
            float bias[4][4];
#pragma unroll
            for (int r = 0; r < 4; ++r) {
                int q = mqu * 16 + (l4 << 2) + r;
                int yi = q >> 3, xi = q & 7;
#pragma unroll
                for (int n = 0; n < 4; ++n) {
                    int key = n * 16 + l15;
                    int yj = key >> 3, xj = key & 7;
                    float b = rpb[((yi - yj + 7) * 15 + (xi - xj + 7)) * 6 + h];
                    if (ty || tx) {
                        int li = (ty ? (yi < 4 ? 1 : 2) : 0) * 3 + (tx ? (xi < 4 ? 1 : 2) : 0);
                        int lj = (ty ? (yj < 4 ? 1 : 2) : 0) * 3 + (tx ? (xj < 4 ? 1 : 2) : 0);
                        if (li != lj) b -= 100.f;
                    }
                    bias[r][n] = b;
                }
            }
            // row softmax (row = (l4,r), 16 lanes hold the 64 keys)
            float inv[4];
#pragma unroll
            for (int r = 0; r < 4; ++r) {
                float vv[4];
                float best = -1e30f;
#pragma unroll
                for (int n = 0; n < 4; ++n) {
                    float v = S[n][r] + bias[r][n];
                    vv[n] = v;
                    best = fmaxf(best, v);
                }
#pragma unroll
                for (int o = 1; o < 16; o <<= 1) best = fmaxf(best, __shfl_xor(best, o));
                float ssum = 0.f;
#pragma unroll
                for (int n = 0; n < 4; ++n) { vv[n] = __expf(vv[n] - best); ssum += vv[n]; }
#pragma unroll
                for (int o = 1; o < 16; o <<= 1) ssum += __shfl_xor(ssum, o);
                inv[r] = 1.f / ssum;
                int qloc = (l4 << 2) + r;
#pragma unroll
                for (int n = 0; n < 4; ++n)
                    Pw[sw(qloc, n * 16 + l15, 64)] = f2b(vv[n]);   // unnormalized P
            }
            // wave-local LDS transpose: DS pipe in-order per wave
            asm volatile("s_waitcnt lgkmcnt(0)" ::: "memory");
            // PV: out[16 q][32 d] = P[16][64] x V[64][32]
            f32x4 O[2];
#pragma unroll
            for (int n = 0; n < 2; ++n) O[n] = (f32x4){0.f, 0.f, 0.f, 0.f};
#pragma unroll
            for (int ksub = 0; ksub < 2; ++ksub) {
                int kk = ksub * 32 + kk0;
                bf16x8 pa = *(const bf16x8*)&Pw[sw(l15, kk, 64)];
#pragma unroll
                for (int n = 0; n < 2; ++n) {
                    bf16x8 vb = *(const bf16x8*)&Vt[h * 2048 + sw(n * 16 + l15, kk, 64)];
                    O[n] = __builtin_amdgcn_mfma_f32_16x16x32_bf16(pa, vb, O[n], 0, 0, 0);
                }
            }
#pragma unroll
            for (int n = 0; n < 2; ++n)
#pragma unroll
            for (int r = 0; r < 4; ++r) {
                int q = mqu * 16 + (l4 << 2) + r;
                AO[sw(q, h * 32 + n * 16 + l15, 192)] = f2b(O[n][r] * inv[r]);
            }
        }
    }
    __syncthreads();

    // --- Phase 4: proj GEMM (waves 0-11, ks-outer) + residual(x) -> o1f -----
    if (wave < 12) {
        const bf16* Wp = wsb + WP_OFF;
        f32x4 acc[4];
#pragma unroll
        for (int m = 0; m < 4; ++m) acc[m] = (f32x4){0.f, 0.f, 0.f, 0.f};
#pragma unroll
        for (int ks = 0; ks < 6; ++ks) {
            bf16x8 bb = *(const bf16x8*)&Wp[(wave * 6 + ks) * 512 + (lane << 3)];
#pragma unroll
            for (int m = 0; m < 4; ++m) {
                bf16x8 a = *(const bf16x8*)&AO[sw(m * 16 + l15, ks * 32 + kk0, 192)];
                acc[m] = __builtin_amdgcn_mfma_f32_16x16x32_bf16(a, bb, acc[m], 0, 0, 0);
            }
        }
        int col = wave * 16 + l15;
        float pb = pbias[col];
#pragma unroll
        for (int m = 0; m < 4; ++m)
#pragma unroll
        for (int r = 0; r < 4; ++r) {
            int tok = m * 16 + (l4 << 2) + r;
            int i = tok >> 3, j = tok & 7;
            int dh = (wh * 8 + i + 4) & 127;
            int dw = (ww * 8 + j + 4) & 127;
            size_t dst = ((size_t)bz * 16384 + dh * 128 + dw) * 192 + col;
            o1f[swf(tok, col)] = acc[m][r] + pb + x[dst];   // x: L2/L3 hit
        }
    }
    __syncthreads();

    // --- Phase 5: LN2 (from LDS) -> As --------------------------------------
    {
        float g0 = g2[lane], g1 = g2[lane + 64], gx = g2[lane + 128];
        float c0 = bt2[lane], c1 = bt2[lane + 64], c2 = bt2[lane + 128];
        for (int t = wave; t < 64; t += 16) {
            float v0 = o1f[swf(t, lane)], v1 = o1f[swf(t, lane + 64)], v2 = o1f[swf(t, lane + 128)];
            float s = v0 + v1 + v2, ss = v0 * v0 + v1 * v1 + v2 * v2;
#pragma unroll
            for (int o = 32; o > 0; o >>= 1) { s += __shfl_xor(s, o); ss += __shfl_xor(ss, o); }
            float mu = s * (1.f / 192.f);
            float var = fmaxf(ss * (1.f / 192.f) - mu * mu, 0.f);
            float rs = rsqrtf(var + 1e-5f);
            As[sw(t, lane, 192)]       = f2b((v0 - mu) * rs * g0 + c0);
            As[sw(t, lane + 64, 192)]  = f2b((v1 - mu) * rs * g1 + c1);
            As[sw(t, lane + 128, 192)] = f2b((v2 - mu) * rs * gx + c2);
        }
    }
    __syncthreads();

    // --- Phase 6: MLP, ks-outer fc1; fc2 = 6 waves x 2 n-frags --------------
    {
        const bf16* W1 = wsb + W1_OFF;
        const bf16* W2 = wsb + W2_OFF;
        f32x4 c2A[4], c2B[4];   // fc2 persistent partials (waves 0-5)
#pragma unroll
        for (int m = 0; m < 4; ++m) {
            c2A[m] = (f32x4){0.f, 0.f, 0.f, 0.f};
            c2B[m] = (f32x4){0.f, 0.f, 0.f, 0.f};
        }

#pragma unroll 1
        for (int ch = 0; ch < 2; ++ch) {
            // fc1 chunk (384 cols): frags {wave}; waves 0-7 also {wave+16}
            {
                int f0 = wave, f1 = wave + 16;     // within-chunk frag ids
                f32x4 aA[4], aB[4];
#pragma unroll
                for (int m = 0; m < 4; ++m) {
                    aA[m] = (f32x4){0.f, 0.f, 0.f, 0.f};
                    aB[m] = (f32x4){0.f, 0.f, 0.f, 0.f};
                }
#pragma unroll
                for (int ks = 0; ks < 6; ++ks) {
                    bf16x8 a[4];
#pragma unroll
                    for (int m = 0; m < 4; ++m)
                        a[m] = *(const bf16x8*)&As[sw(m * 16 + l15, ks * 32 + kk0, 192)];
                    bf16x8 b0 = *(const bf16x8*)&W1[((ch * 24 + f0) * 6 + ks) * 512 + (lane << 3)];
#pragma unroll
                    for (int m = 0; m < 4; ++m)
                        aA[m] = __builtin_amdgcn_mfma_f32_16x16x32_bf16(a[m], b0, aA[m], 0, 0, 0);
                    if (wave < 8) {
                        bf16x8 b1 = *(const bf16x8*)&W1[((ch * 24 + f1) * 6 + ks) * 512 + (lane << 3)];
#pragma unroll
                        for (int m = 0; m < 4; ++m)
                            aB[m] = __builtin_amdgcn_mfma_f32_16x16x32_bf16(a[m], b1, aB[m], 0, 0, 0);
                    }
                }
                auto EPI1 = [&](int fl, f32x4* acc) {
                    int colc = fl * 16 + l15;
                    float bb1 = b1[(ch * 24 + fl) * 16 + l15];
#pragma unroll
                    for (int m = 0; m < 4; ++m)
#pragma unroll
                    for (int r = 0; r < 4; ++r) {
                        float v = acc[m][r] + bb1;
                        v = v > 0.f ? v : 0.2f * v;
                        Hs[sw(m * 16 + (l4 << 2) + r, colc, 384)] = f2b(v);
                    }
                };
                EPI1(f0, aA);
                if (wave < 8) EPI1(f1, aB);
            }
            __syncthreads();
            // fc2 partial: waves 0-5, n-frags {2*wave, 2*wave+1}, K += 384
            if (wave < 6) {
                int f0 = wave * 2, f1 = wave * 2 + 1;
#pragma unroll
                for (int ks = 0; ks < 12; ++ks) {
                    bf16x8 a[4];
#pragma unroll
                    for (int m = 0; m < 4; ++m)
                        a[m] = *(const bf16x8*)&Hs[sw(m * 16 + l15, ks * 32 + kk0, 384)];
                    bf16x8 w0 = *(const bf16x8*)&W2[(f0 * 24 + ch * 12 + ks) * 512 + (lane << 3)];
                    bf16x8 w1v = *(const bf16x8*)&W2[(f1 * 24 + ch * 12 + ks) * 512 + (lane << 3)];
#pragma unroll
                    for (int m = 0; m < 4; ++m)
                        c2A[m] = __builtin_amdgcn_mfma_f32_16x16x32_bf16(a[m], w0, c2A[m], 0, 0, 0);
#pragma unroll
                    for (int m = 0; m < 4; ++m)
                        c2B[m] = __builtin_amdgcn_mfma_f32_16x16x32_bf16(a[m], w1v, c2B[m], 0, 0, 0);
                }
            }
            if (ch == 0) __syncthreads();   // next fc1 overwrites Hs
        }

        // --- Phase 7: final = o1f + fc2 + b2, window-reverse + un-shift -----
        if (wave < 6) {
            auto STORE = [&](int f, f32x4* acc) {
                int col = f * 16 + l15;
                float bb2 = b2[col];
#pragma unroll
                for (int m = 0; m < 4; ++m)
#pragma unroll
                for (int r = 0; r < 4; ++r) {
                    int tok = m * 16 + (l4 << 2) + r;
                    int i = tok >> 3, j = tok & 7;
                    int dh = (wh * 8 + i + 4) & 127;
                    int dw = (ww * 8 + j + 4) & 127;
                    size_t dst = ((size_t)bz * 16384 + dh * 128 + dw) * 192 + col;
                    out[dst] = acc[m][r] + bb2 + o1f[swf(tok, col)];
                }
            };
            STORE(wave * 2, c2A);
            STORE(wave * 2 + 1, c2B);
        }
    }
}

// ---------------- launch ----------------------------------------------------
extern "C" void kernel_launch(void* const* d_in, const int* in_sizes, int n_in,
                              void* d_out, int out_size, void* d_ws, size_t ws_size,
                              hipStream_t stream) {
    const float* x     = (const float*)d_in[0];
    const float* n1g   = (const float*)d_in[1];
    const float* n1b   = (const float*)d_in[2];
    const float* qkvw  = (const float*)d_in[3];
    const float* qkvb  = (const float*)d_in[4];
    const float* projw = (const float*)d_in[5];
    const float* projb = (const float*)d_in[6];
    const float* rpb   = (const float*)d_in[7];
    const float* n2g   = (const float*)d_in[8];
    const float* n2b   = (const float*)d_in[9];
    const float* fc1w  = (const float*)d_in[10];
    const float* fc1b  = (const float*)d_in[11];
    const float* fc2w  = (const float*)d_in[12];
    const float* fc2b  = (const float*)d_in[13];

    float* out = (float*)d_out;
    bf16* wsb  = (bf16*)d_ws;                       // 884736 B weights
    (void)ws_size; (void)in_sizes; (void)n_in; (void)out_size;

    w_cvt<<<216, 256, 0, stream>>>(qkvw, projw, fc1w, fc2w, wsb);
    k_all<<<2048, 1024, 0, stream>>>(x, n1g, n1b, wsb, rpb, qkvb, projb,
                                     n2g, n2b, fc1b, fc2b, out);
}